// Round 7
// baseline (446.373 us; speedup 1.0000x reference)
//
#include <hip/hip_runtime.h>
#include <cstdint>
#include <cstddef>

#define SEQ 2048
#define DIMM 2048
#define NHEADS 8
#define HDIM 256
#define BATCH 2
#define NROWS 4096      // BATCH*SEQ
#define EDIM 2048       // NHEADS*HDIM
#define NQKV 6144       // 3*EDIM
#define SCALE 0.0625f   // 1/sqrt(256)
#define LOG2E 1.44269504f

typedef __attribute__((ext_vector_type(8))) short bf16x8;   // 8 bf16 in 4 VGPRs
typedef __attribute__((ext_vector_type(4))) float f32x4;
typedef unsigned short u16;
typedef unsigned int u32;

__device__ __forceinline__ u16 f2bf(float f) {
  union { float f; u32 u; } v; v.f = f;
  u32 r = (v.u + 0x7fffu + ((v.u >> 16) & 1u)) >> 16;   // RNE
  return (u16)r;
}
__device__ __forceinline__ float bf2f(u16 b) {
  union { u32 u; float f; } v; v.u = ((u32)b) << 16;
  return v.f;
}
// async global->LDS, 16B per lane. LDS layout must be lane-linear (wave base + lane*16).
__device__ __forceinline__ void gload16(const void* g, void* l) {
  __builtin_amdgcn_global_load_lds(
      (__attribute__((address_space(1))) void*)(void*)g,
      (__attribute__((address_space(3))) void*)l, 16, 0, 0);
}

// ---------------- fused fp32 -> bf16 cast for all 5 tensors ----------------
__global__ void __launch_bounds__(256) cast_all(const float4* __restrict__ x,
                                                const float4* __restrict__ wq,
                                                const float4* __restrict__ wk,
                                                const float4* __restrict__ wv,
                                                const float4* __restrict__ wo,
                                                ushort4* __restrict__ xb,
                                                ushort4* __restrict__ wcat,
                                                ushort4* __restrict__ wob) {
  const long i = (long)blockIdx.x * 256 + threadIdx.x;
  const float4* src; ushort4* dst; long off;
  if (i < 2097152L)       { src = x;  dst = xb;              off = i; }
  else if (i < 3145728L)  { src = wq; dst = wcat;            off = i - 2097152L; }
  else if (i < 4194304L)  { src = wk; dst = wcat + 1048576L; off = i - 3145728L; }
  else if (i < 5242880L)  { src = wv; dst = wcat + 2097152L; off = i - 4194304L; }
  else                    { src = wo; dst = wob;             off = i - 5242880L; }
  const float4 v = src[off];
  ushort4 o;
  o.x = f2bf(v.x); o.y = f2bf(v.y); o.z = f2bf(v.z); o.w = f2bf(v.w);
  dst[off] = o;
}

// ---------------- GEMM: C(MxN) = A(MxK) * B(NxK)^T, bf16 in, fp32 acc ----------------
// 128x128 tile, BK=64, 4 waves, each wave a 64x64 quadrant (4x4 of 16x16x32 MFMA).
template<int BF16OUT>
__global__ void __launch_bounds__(256) gemm_bt(const u16* __restrict__ A,
                                               const u16* __restrict__ B,
                                               void* __restrict__ Cout,
                                               int N, int K) {
  __shared__ __align__(16) u16 As[128 * 64];
  __shared__ __align__(16) u16 Bs[128 * 64];
  const int tid = threadIdx.x;
  const int wave = tid >> 6, lane = tid & 63;
  const int quad = lane >> 4, l16 = lane & 15;
  const long bm = (long)blockIdx.x * 128, bn = (long)blockIdx.y * 128;
  const int wm = (wave >> 1) * 64, wn = (wave & 1) * 64;
  const f32x4 fz = {0.f, 0.f, 0.f, 0.f};
  f32x4 acc[4][4];
#pragma unroll
  for (int i = 0; i < 4; ++i)
#pragma unroll
    for (int j = 0; j < 4; ++j) acc[i][j] = fz;

  for (int k0 = 0; k0 < K; k0 += 64) {
#pragma unroll
    for (int p = 0; p < 4; ++p) {
      const int o = p * 4096 + tid * 16;           // byte offset in 16KB tile
      const int row = o >> 7;                      // 128B rows
      const int cg = ((o >> 4) & 7) ^ (row & 7);   // swizzled source unit
      gload16(A + (bm + row) * (long)K + k0 + cg * 8, (char*)As + o);
      gload16(B + (bn + row) * (long)K + k0 + cg * 8, (char*)Bs + o);
    }
    __syncthreads();
#pragma unroll
    for (int ks = 0; ks < 2; ++ks) {
      bf16x8 af[4], bfr[4];
#pragma unroll
      for (int t = 0; t < 4; ++t) {
        const int ar = wm + t * 16 + l16;
        const int br = wn + t * 16 + l16;
        const int u = ks * 4 + quad;
        af[t]  = *(const bf16x8*)(As + ar * 64 + (u ^ (ar & 7)) * 8);
        bfr[t] = *(const bf16x8*)(Bs + br * 64 + (u ^ (br & 7)) * 8);
      }
#pragma unroll
      for (int i = 0; i < 4; ++i)
#pragma unroll
        for (int j = 0; j < 4; ++j)
          acc[i][j] = __builtin_amdgcn_mfma_f32_16x16x32_bf16(af[i], bfr[j], acc[i][j], 0, 0, 0);
    }
    __syncthreads();
  }
  // epilogue: C/D layout col=lane&15, row=quad*4+reg  [m89-verified]
#pragma unroll
  for (int i = 0; i < 4; ++i)
#pragma unroll
    for (int j = 0; j < 4; ++j)
#pragma unroll
      for (int r = 0; r < 4; ++r) {
        const long row = bm + wm + i * 16 + quad * 4 + r;
        const long col = bn + wn + j * 16 + l16;
        const float v = acc[i][j][r];
        if (BF16OUT) ((u16*)Cout)[row * N + col] = f2bf(v);
        else         ((float*)Cout)[row * N + col] = v;
      }
}

// ---------------- fused RMSnorm+RoPE (q/k) + V transpose, one launch ----------------
// blocks [0,16384): norm jobs (4 waves x 1 row each); blocks [16384,18432): V transpose
__global__ void __launch_bounds__(256) norm_rope_tv(u16* __restrict__ qkv,
                                                    const int* __restrict__ pos_ids,
                                                    const float* __restrict__ qw,
                                                    const float* __restrict__ kw,
                                                    u16* __restrict__ vt) {
  __shared__ u16 tile[64][73];
  if (blockIdx.x < 16384) {
    const int job = blockIdx.x * 4 + (threadIdx.x >> 6);
    const int lane = threadIdx.x & 63;
    const int which = job >> 15;       // 0 = q, 1 = k
    const int j2 = job & 32767;
    const int r = j2 >> 3;             // row 0..4095 (b*S+s)
    const int h = j2 & 7;
    const int s = r & (SEQ - 1);
    const int pos = pos_ids[s];
    const float* w = which ? kw : qw;
    u16* p = qkv + (long)r * NQKV + which * EDIM + h * HDIM;

    float x0 = bf2f(p[lane]);
    float x1 = bf2f(p[lane + 64]);
    float x2 = bf2f(p[lane + 128]);
    float x3 = bf2f(p[lane + 192]);
    float ss = x0 * x0 + x1 * x1 + x2 * x2 + x3 * x3;
#pragma unroll
    for (int off = 1; off < 64; off <<= 1) ss += __shfl_xor(ss, off);
    const float rinv = rsqrtf(ss * (1.0f / HDIM) + 1e-6f);
    x0 *= rinv * w[lane];       x1 *= rinv * w[lane + 64];
    x2 *= rinv * w[lane + 128]; x3 *= rinv * w[lane + 192];
    const float L2TEN4 = 13.287712379549449f;  // log2(10000)
    const float f0 = exp2f(-(2.0f * lane / HDIM) * L2TEN4);
    const float f1 = exp2f(-(2.0f * (lane + 64) / HDIM) * L2TEN4);
    const float a0 = pos * f0, a1 = pos * f1;
    float s0, c0, s1, c1;
    __sincosf(a0, &s0, &c0);
    __sincosf(a1, &s1, &c1);
    p[lane]       = f2bf(x0 * c0 - x2 * s0);
    p[lane + 64]  = f2bf(x1 * c1 - x3 * s1);
    p[lane + 128] = f2bf(x2 * c0 + x0 * s0);
    p[lane + 192] = f2bf(x3 * c1 + x1 * s1);
  } else {
    const int t = blockIdx.x - 16384;
    const int tid = threadIdx.x;
    const int st = (t & 31) * 64;
    const int dt = ((t >> 5) & 3) * 64;
    const int bh = t >> 7;
    const int b = bh >> 3, h = bh & 7;
    const u16* src = qkv + (long)(b * SEQ + st) * NQKV + 2 * EDIM + h * HDIM + dt;
#pragma unroll
    for (int p = 0; p < 2; ++p) {
      const int idx = p * 2048 + tid * 8;
      const int sr = idx >> 6, dc = idx & 63;
      const uint4 v = *(const uint4*)(src + (long)sr * NQKV + dc);
      const u16* pv = (const u16*)&v;
#pragma unroll
      for (int e = 0; e < 8; ++e) tile[sr][dc + e] = pv[e];
    }
    __syncthreads();
    u16* dst = vt + ((long)bh * HDIM + dt) * SEQ + st;
#pragma unroll
    for (int p = 0; p < 2; ++p) {
      const int idx = p * 2048 + tid * 8;
      const int dr = idx >> 6, sc = idx & 63;
      u16 tmp[8];
#pragma unroll
      for (int e = 0; e < 8; ++e) tmp[e] = tile[sc + e][dr];
      *(uint4*)(dst + (long)dr * SEQ + sc) = *(const uint4*)tmp;
    }
  }
}

// ---------------- flash attention v7: q-tile 128, 32 q-rows/wave, no k-split --------
// Each wave owns 32 q-rows (2 row-tiles) x full 32-k x full 256-d: kf/vf fragments
// reused across both row-tiles -> LDS reads per MFMA halved vs v6; staged K/V bytes
// halved (half as many blocks). P stays wave-private (no extra barrier). Pipelined
// 2-barrier loop: syncA -> issue V[kt] -> QK -> exp/P -> syncB -> issue K[kt+1] -> PV.
// Fixed-max softmax (|score|<=16); split-K chunks of 32 k-tiles; qt<8 single-owner.
__global__ void __launch_bounds__(256, 2) flash_attn(const u16* __restrict__ qkv,
                                                     const u16* __restrict__ vt,
                                                     u16* __restrict__ opart,
                                                     float* __restrict__ lpart,
                                                     u16* __restrict__ ob) {
  const int bh = blockIdx.x, b = bh >> 3, h = bh & 7;
  const int qt = 15 - (int)blockIdx.y;          // 128-row q-tiles, heavy first
  const int kc = blockIdx.z;
  if (kc && qt < 8) return;                     // single chunk suffices
  const int kt0 = kc * 32;                      // 32-seq k-tiles
  const int ktmax = 4 * qt + 3;
  const int kt_end = (ktmax < kt0 + 31) ? ktmax : (kt0 + 31);

  __shared__ __align__(16) u16 Ks[32 * 256];    // 16 KB
  __shared__ __align__(16) u16 Vs[256 * 32];    // 16 KB
  __shared__ __align__(16) u16 Pb[4 * 32 * 32]; //  8 KB (per-wave private slices)
  const int tid = threadIdx.x;
  const int wave = tid >> 6, lane = tid & 63;
  const int quad = lane >> 4, l16 = lane & 15;
  const long qbase = (long)(b * SEQ + qt * 128) * NQKV + h * HDIM;
  const long kbase = (long)(b * SEQ) * NQKV + EDIM + h * HDIM;
  const long vbase = (long)bh * HDIM * SEQ;

  // Q fragments straight from global into regs: 2 row-tiles x 8 k-steps
  bf16x8 qf[2][8];
#pragma unroll
  for (int rt = 0; rt < 2; ++rt) {
    const u16* qrow = qkv + qbase + (long)(wave * 32 + rt * 16 + l16) * NQKV + quad * 8;
#pragma unroll
    for (int ks = 0; ks < 8; ++ks)
      qf[rt][ks] = *(const bf16x8*)(qrow + ks * 32);
  }

  // preload K[kt0]: 32 rows x 256 d (512B rows, unit swizzle u^(row&7))
#pragma unroll
  for (int p = 0; p < 4; ++p) {
    const int o = p * 4096 + tid * 16;
    const int row = o >> 9;
    const int cg = ((o >> 4) & 31) ^ (row & 7);
    gload16(qkv + kbase + (long)(kt0 * 32 + row) * NQKV + cg * 8, (char*)Ks + o);
  }

  const f32x4 fz = {0.f, 0.f, 0.f, 0.f};
  f32x4 O[2][16];
#pragma unroll
  for (int rt = 0; rt < 2; ++rt)
#pragma unroll
    for (int t = 0; t < 16; ++t) O[rt][t] = fz;
  float lacc[2][4];
#pragma unroll
  for (int rt = 0; rt < 2; ++rt)
#pragma unroll
    for (int r = 0; r < 4; ++r) lacc[rt][r] = 0.f;
  const float C1 = SCALE * LOG2E;       // exp2(S*C1 - C2) = exp(score - 16)
  const float C2 = 16.0f * LOG2E;

  for (int kt = kt0; kt <= kt_end; ++kt) {
    __syncthreads();  // syncA: K[kt] staged; prev PV reads of Vs done
    // issue V[kt] -> Vs (256 d-rows x 32 k, 64B rows, swizzle u^(row&3))
#pragma unroll
    for (int p = 0; p < 4; ++p) {
      const int o = p * 4096 + tid * 16;
      const int row = o >> 6;
      const int cg = ((o >> 4) & 3) ^ (row & 3);
      gload16(vt + vbase + (long)row * SEQ + kt * 32 + cg * 8, (char*)Vs + o);
    }
    // S = Q·K^T : per wave 32 q-rows x 32 k-cols; kf read once, reused for both rt
    f32x4 S[2][2];
    S[0][0] = fz; S[0][1] = fz; S[1][0] = fz; S[1][1] = fz;
#pragma unroll
    for (int ks = 0; ks < 8; ++ks) {
      bf16x8 kf[2];
#pragma unroll
      for (int nt = 0; nt < 2; ++nt) {
        const int kr = nt * 16 + l16;
        const int u = ks * 4 + quad;
        kf[nt] = *(const bf16x8*)(Ks + kr * 256 + (u ^ (kr & 7)) * 8);
      }
#pragma unroll
      for (int rt = 0; rt < 2; ++rt)
#pragma unroll
        for (int nt = 0; nt < 2; ++nt)
          S[rt][nt] = __builtin_amdgcn_mfma_f32_16x16x32_bf16(qf[rt][ks], kf[nt], S[rt][nt], 0, 0, 0);
    }
    // exp + causal mask + write P (wave-private, 32x32, 64B rows, swizzle u^(row&3))
    u16* Pw = Pb + wave * (32 * 32);
    const bool diag = (kt >= 4 * qt);
#pragma unroll
    for (int rt = 0; rt < 2; ++rt) {
      const int qg0 = qt * 128 + wave * 32 + rt * 16 + quad * 4;
#pragma unroll
      for (int nt = 0; nt < 2; ++nt) {
        const int kg = kt * 32 + nt * 16 + l16;
#pragma unroll
        for (int r = 0; r < 4; ++r) {
          float p = exp2f(S[rt][nt][r] * C1 - C2);
          if (diag) p = (kg <= qg0 + r) ? p : 0.f;
          lacc[rt][r] += p;
          const int qrow = rt * 16 + quad * 4 + r;
          const int col = nt * 16 + l16;
          Pw[qrow * 32 + (((col >> 3) ^ (qrow & 3)) * 8) + (col & 7)] = f2bf(p);
        }
      }
    }
    __syncthreads();  // syncB: V[kt] staged; Ks reads done
    // issue K[kt+1] -> Ks; flight covered by PV below
    if (kt < kt_end) {
#pragma unroll
      for (int p = 0; p < 4; ++p) {
        const int o = p * 4096 + tid * 16;
        const int row = o >> 9;
        const int cg = ((o >> 4) & 31) ^ (row & 7);
        gload16(qkv + kbase + (long)((kt + 1) * 32 + row) * NQKV + cg * 8, (char*)Ks + o);
      }
    }
    // O += P·V : vf read once, reused for both rt
    bf16x8 pf[2];
#pragma unroll
    for (int rt = 0; rt < 2; ++rt) {
      const int pr = rt * 16 + l16;
      pf[rt] = *(const bf16x8*)(Pw + pr * 32 + ((quad ^ (pr & 3)) * 8));
    }
#pragma unroll
    for (int nt = 0; nt < 16; ++nt) {
      const int vr = nt * 16 + l16;
      const bf16x8 vf = *(const bf16x8*)(Vs + vr * 32 + ((quad ^ (vr & 3)) * 8));
#pragma unroll
      for (int rt = 0; rt < 2; ++rt)
        O[rt][nt] = __builtin_amdgcn_mfma_f32_16x16x32_bf16(pf[rt], vf, O[rt][nt], 0, 0, 0);
    }
  }
  // reduce per-lane l partial across the 16 lanes sharing a row group
#pragma unroll
  for (int off = 1; off < 16; off <<= 1)
#pragma unroll
    for (int rt = 0; rt < 2; ++rt)
#pragma unroll
      for (int r = 0; r < 4; ++r) lacc[rt][r] += __shfl_xor(lacc[rt][r], off);

  if (qt < 8) {
    // sole owner: normalize and write Ob directly
#pragma unroll
    for (int rt = 0; rt < 2; ++rt) {
      float rinv[4];
#pragma unroll
      for (int r = 0; r < 4; ++r) rinv[r] = 1.0f / lacc[rt][r];
      const long obase = (long)(b * SEQ + qt * 128 + wave * 32 + rt * 16) * EDIM + h * HDIM;
#pragma unroll
      for (int nt = 0; nt < 16; ++nt) {
        const int col = nt * 16 + l16;
#pragma unroll
        for (int r = 0; r < 4; ++r)
          ob[obase + (long)(quad * 4 + r) * EDIM + col] = f2bf(O[rt][nt][r] * rinv[r]);
      }
    }
  } else {
    const long pbase = ((long)(bh * 16 + qt) * 2 + kc) * (128 * 256);
#pragma unroll
    for (int rt = 0; rt < 2; ++rt)
#pragma unroll
      for (int nt = 0; nt < 16; ++nt) {
        const int col = nt * 16 + l16;
#pragma unroll
        for (int r = 0; r < 4; ++r) {
          const int qrow = wave * 32 + rt * 16 + quad * 4 + r;
          opart[pbase + (long)qrow * 256 + col] = f2bf(O[rt][nt][r]);
        }
      }
    if (l16 == 0) {
      const long lbase = ((long)(bh * 16 + qt) * 2 + kc) * 128;
#pragma unroll
      for (int rt = 0; rt < 2; ++rt)
#pragma unroll
        for (int r = 0; r < 4; ++r)
          lpart[lbase + wave * 32 + rt * 16 + quad * 4 + r] = lacc[rt][r];
    }
  }
}

// ---------------- combine split-K partials (qt>=8): Ob = (O0+O1)/(l0+l1) -------------
__global__ void __launch_bounds__(256) fa_combine(const u16* __restrict__ opart,
                                                  const float* __restrict__ lpart,
                                                  u16* __restrict__ ob) {
  const int bh = blockIdx.x, qt = 8 + blockIdx.y;
  const int b = bh >> 3, h = bh & 7;
  const long p0 = ((long)(bh * 16 + qt) * 2) * (128 * 256);
  const long l0 = ((long)(bh * 16 + qt) * 2) * 128;
  __shared__ float rl[128];
  if (threadIdx.x < 128) {
    float l = lpart[l0 + threadIdx.x] + lpart[l0 + 128 + threadIdx.x];
    rl[threadIdx.x] = 1.0f / l;
  }
  __syncthreads();
#pragma unroll
  for (int i = 0; i < 16; ++i) {
    const int e = i * 2048 + threadIdx.x * 8;
    const int row = e >> 8, d = e & 255;
    const u16* a = opart + p0 + e;
    const u16* c = a + 128 * 256;
    float v[8];
#pragma unroll
    for (int j = 0; j < 8; ++j) v[j] = bf2f(a[j]) + bf2f(c[j]);
    const float inv = rl[row];
    u16 o[8];
#pragma unroll
    for (int j = 0; j < 8; ++j) o[j] = f2bf(v[j] * inv);
    *(uint4*)(ob + ((long)(b * SEQ + qt * 128 + row)) * EDIM + h * HDIM + d) =
        *(const uint4*)o;
  }
}

// ---------------- launch ----------------
extern "C" void kernel_launch(void* const* d_in, const int* in_sizes, int n_in,
                              void* d_out, int out_size, void* d_ws, size_t ws_size,
                              hipStream_t stream) {
  const float* x  = (const float*)d_in[0];
  const int* pos  = (const int*)d_in[1];
  const float* Wq = (const float*)d_in[2];
  const float* Wk = (const float*)d_in[3];
  const float* Wv = (const float*)d_in[4];
  const float* Wo = (const float*)d_in[5];
  const float* qw = (const float*)d_in[6];
  const float* kw = (const float*)d_in[7];

  char* ws = (char*)d_ws;
  u16* xb   = (u16*)(ws);                    // 16 MiB  x bf16 (4096x2048)   [dead after GEMM1]
  u16* Wcat = (u16*)(ws + 16777216L);        // 24 MiB  [Wq;Wk;Wv] bf16     [dead after GEMM1]
  u16* Wob  = (u16*)(ws + 41943040L);        //  8 MiB  Wo bf16
  u16* QKVb = (u16*)(ws + 50331648L);        // 48 MiB  qkv bf16 (4096x6144)
  u16* Vt   = (u16*)(ws + 100663296L);       // 16 MiB  V^T bf16 (16x256x2048)
  u16* Ob   = (u16*)(ws + 117440512L);       // 16 MiB  attn out bf16 (4096x2048)
  // flash partials overlay the dead xb/Wcat region (33.8 MiB < 40 MiB):
  u16*   Opart = (u16*)(ws);                 // 32 MiB  (16*16*2) x 128 x 256 bf16
  float* Lpart = (float*)(ws + 33554432L);   // 256 KiB

  cast_all<<<24576, 256, 0, stream>>>((const float4*)x, (const float4*)Wq,
                                      (const float4*)Wk, (const float4*)Wv,
                                      (const float4*)Wo, (ushort4*)xb,
                                      (ushort4*)Wcat, (ushort4*)Wob);

  gemm_bt<1><<<dim3(32, 48), 256, 0, stream>>>(xb, Wcat, (void*)QKVb, NQKV, DIMM);
  norm_rope_tv<<<18432, 256, 0, stream>>>(QKVb, pos, qw, kw, Vt);
  flash_attn<<<dim3(16, 16, 2), 256, 0, stream>>>(QKVb, Vt, Opart, Lpart, Ob);
  fa_combine<<<dim3(16, 8), 256, 0, stream>>>(Opart, Lpart, Ob);
  gemm_bt<0><<<dim3(32, 16), 256, 0, stream>>>(Ob, Wob, d_out, EDIM, DIMM);
}

// Round 8
// 373.910 us; speedup vs baseline: 1.1938x; 1.1938x over previous
//
#include <hip/hip_runtime.h>
#include <cstdint>
#include <cstddef>

#define SEQ 2048
#define DIMM 2048
#define NHEADS 8
#define HDIM 256
#define BATCH 2
#define NROWS 4096      // BATCH*SEQ
#define EDIM 2048       // NHEADS*HDIM
#define NQKV 6144       // 3*EDIM
#define SCALE 0.0625f   // 1/sqrt(256)
#define LOG2E 1.44269504f

typedef __attribute__((ext_vector_type(8))) short bf16x8;   // 8 bf16 in 4 VGPRs
typedef __attribute__((ext_vector_type(4))) float f32x4;
typedef __attribute__((ext_vector_type(16))) float f32x16;
typedef unsigned short u16;
typedef unsigned int u32;

__device__ __forceinline__ u16 f2bf(float f) {
  union { float f; u32 u; } v; v.f = f;
  u32 r = (v.u + 0x7fffu + ((v.u >> 16) & 1u)) >> 16;   // RNE
  return (u16)r;
}
__device__ __forceinline__ float bf2f(u16 b) {
  union { u32 u; float f; } v; v.u = ((u32)b) << 16;
  return v.f;
}
// async global->LDS, 16B per lane. LDS layout must be lane-linear (wave base + lane*16).
__device__ __forceinline__ void gload16(const void* g, void* l) {
  __builtin_amdgcn_global_load_lds(
      (__attribute__((address_space(1))) void*)(void*)g,
      (__attribute__((address_space(3))) void*)l, 16, 0, 0);
}

// ---------------- fused fp32 -> bf16 cast for all 5 tensors ----------------
__global__ void __launch_bounds__(256) cast_all(const float4* __restrict__ x,
                                                const float4* __restrict__ wq,
                                                const float4* __restrict__ wk,
                                                const float4* __restrict__ wv,
                                                const float4* __restrict__ wo,
                                                ushort4* __restrict__ xb,
                                                ushort4* __restrict__ wcat,
                                                ushort4* __restrict__ wob) {
  const long i = (long)blockIdx.x * 256 + threadIdx.x;
  const float4* src; ushort4* dst; long off;
  if (i < 2097152L)       { src = x;  dst = xb;              off = i; }
  else if (i < 3145728L)  { src = wq; dst = wcat;            off = i - 2097152L; }
  else if (i < 4194304L)  { src = wk; dst = wcat + 1048576L; off = i - 3145728L; }
  else if (i < 5242880L)  { src = wv; dst = wcat + 2097152L; off = i - 4194304L; }
  else                    { src = wo; dst = wob;             off = i - 5242880L; }
  const float4 v = src[off];
  ushort4 o;
  o.x = f2bf(v.x); o.y = f2bf(v.y); o.z = f2bf(v.z); o.w = f2bf(v.w);
  dst[off] = o;
}

// ---------------- GEMM: C(MxN) = A(MxK) * B(NxK)^T, bf16 in, fp32 acc ----------------
// 128x128 tile, BK=64, 4 waves, each wave a 64x64 quadrant = 2x2 of 32x32x16 MFMA.
// 32x32 shape: half the MFMA instructions of 16x16x32 at same LDS traffic; A/B frag
// mapping m=lane&31, k=(lane>>5)*8+j; C/D col=lane&31, row=(reg&3)+8*(reg>>2)+4*(lane>>5)
// [m74/m101; full chain HW-validated by our r4 fp8 run on this workload].
template<int BF16OUT>
__global__ void __launch_bounds__(256) gemm_bt(const u16* __restrict__ A,
                                               const u16* __restrict__ B,
                                               void* __restrict__ Cout,
                                               int N, int K) {
  __shared__ __align__(16) u16 As[128 * 64];
  __shared__ __align__(16) u16 Bs[128 * 64];
  const int tid = threadIdx.x;
  const int wave = tid >> 6, lane = tid & 63;
  const int l32 = lane & 31, half = lane >> 5;
  const long bm = (long)blockIdx.x * 128, bn = (long)blockIdx.y * 128;
  const int wm = (wave >> 1) * 64, wn = (wave & 1) * 64;
  f32x16 acc[2][2];
#pragma unroll
  for (int i = 0; i < 2; ++i)
#pragma unroll
    for (int j = 0; j < 2; ++j)
#pragma unroll
      for (int r = 0; r < 16; ++r) acc[i][j][r] = 0.f;

  for (int k0 = 0; k0 < K; k0 += 64) {
#pragma unroll
    for (int p = 0; p < 4; ++p) {
      const int o = p * 4096 + tid * 16;           // byte offset in 16KB tile
      const int row = o >> 7;                      // 128B rows
      const int cg = ((o >> 4) & 7) ^ (row & 7);   // swizzled source unit
      gload16(A + (bm + row) * (long)K + k0 + cg * 8, (char*)As + o);
      gload16(B + (bn + row) * (long)K + k0 + cg * 8, (char*)Bs + o);
    }
    __syncthreads();
#pragma unroll
    for (int ks = 0; ks < 4; ++ks) {
      bf16x8 af[2], bfr[2];
#pragma unroll
      for (int t = 0; t < 2; ++t) {
        const int ar = wm + t * 32 + l32;
        const int br = wn + t * 32 + l32;
        const int u = ks * 2 + half;               // k = ks*16 + half*8
        af[t]  = *(const bf16x8*)(As + ar * 64 + ((u ^ (ar & 7)) * 8));
        bfr[t] = *(const bf16x8*)(Bs + br * 64 + ((u ^ (br & 7)) * 8));
      }
#pragma unroll
      for (int i = 0; i < 2; ++i)
#pragma unroll
        for (int j = 0; j < 2; ++j)
          acc[i][j] = __builtin_amdgcn_mfma_f32_32x32x16_bf16(af[i], bfr[j], acc[i][j], 0, 0, 0);
    }
    __syncthreads();
  }
  // epilogue: 32x32 C/D layout col=lane&31, row=(reg&3)+8*(reg>>2)+4*half
#pragma unroll
  for (int i = 0; i < 2; ++i)
#pragma unroll
    for (int j = 0; j < 2; ++j)
#pragma unroll
      for (int r = 0; r < 16; ++r) {
        const long row = bm + wm + i * 32 + (r & 3) + 8 * (r >> 2) + 4 * half;
        const long col = bn + wn + j * 32 + l32;
        const float v = acc[i][j][r];
        if (BF16OUT) ((u16*)Cout)[row * N + col] = f2bf(v);
        else         ((float*)Cout)[row * N + col] = v;
      }
}

// ---------------- fused RMSnorm+RoPE (q/k) + V transpose, one launch ----------------
// blocks [0,16384): norm jobs (4 waves x 1 row each); blocks [16384,18432): V transpose
__global__ void __launch_bounds__(256) norm_rope_tv(u16* __restrict__ qkv,
                                                    const int* __restrict__ pos_ids,
                                                    const float* __restrict__ qw,
                                                    const float* __restrict__ kw,
                                                    u16* __restrict__ vt) {
  __shared__ u16 tile[64][73];
  if (blockIdx.x < 16384) {
    const int job = blockIdx.x * 4 + (threadIdx.x >> 6);
    const int lane = threadIdx.x & 63;
    const int which = job >> 15;       // 0 = q, 1 = k
    const int j2 = job & 32767;
    const int r = j2 >> 3;             // row 0..4095 (b*S+s)
    const int h = j2 & 7;
    const int s = r & (SEQ - 1);
    const int pos = pos_ids[s];
    const float* w = which ? kw : qw;
    u16* p = qkv + (long)r * NQKV + which * EDIM + h * HDIM;

    float x0 = bf2f(p[lane]);
    float x1 = bf2f(p[lane + 64]);
    float x2 = bf2f(p[lane + 128]);
    float x3 = bf2f(p[lane + 192]);
    float ss = x0 * x0 + x1 * x1 + x2 * x2 + x3 * x3;
#pragma unroll
    for (int off = 1; off < 64; off <<= 1) ss += __shfl_xor(ss, off);
    const float rinv = rsqrtf(ss * (1.0f / HDIM) + 1e-6f);
    x0 *= rinv * w[lane];       x1 *= rinv * w[lane + 64];
    x2 *= rinv * w[lane + 128]; x3 *= rinv * w[lane + 192];
    const float L2TEN4 = 13.287712379549449f;  // log2(10000)
    const float f0 = exp2f(-(2.0f * lane / HDIM) * L2TEN4);
    const float f1 = exp2f(-(2.0f * (lane + 64) / HDIM) * L2TEN4);
    const float a0 = pos * f0, a1 = pos * f1;
    float s0, c0, s1, c1;
    __sincosf(a0, &s0, &c0);
    __sincosf(a1, &s1, &c1);
    p[lane]       = f2bf(x0 * c0 - x2 * s0);
    p[lane + 64]  = f2bf(x1 * c1 - x3 * s1);
    p[lane + 128] = f2bf(x2 * c0 + x0 * s0);
    p[lane + 192] = f2bf(x3 * c1 + x1 * s1);
  } else {
    const int t = blockIdx.x - 16384;
    const int tid = threadIdx.x;
    const int st = (t & 31) * 64;
    const int dt = ((t >> 5) & 3) * 64;
    const int bh = t >> 7;
    const int b = bh >> 3, h = bh & 7;
    const u16* src = qkv + (long)(b * SEQ + st) * NQKV + 2 * EDIM + h * HDIM + dt;
#pragma unroll
    for (int p = 0; p < 2; ++p) {
      const int idx = p * 2048 + tid * 8;
      const int sr = idx >> 6, dc = idx & 63;
      const uint4 v = *(const uint4*)(src + (long)sr * NQKV + dc);
      const u16* pv = (const u16*)&v;
#pragma unroll
      for (int e = 0; e < 8; ++e) tile[sr][dc + e] = pv[e];
    }
    __syncthreads();
    u16* dst = vt + ((long)bh * HDIM + dt) * SEQ + st;
#pragma unroll
    for (int p = 0; p < 2; ++p) {
      const int idx = p * 2048 + tid * 8;
      const int dr = idx >> 6, sc = idx & 63;
      u16 tmp[8];
#pragma unroll
      for (int e = 0; e < 8; ++e) tmp[e] = tile[sc + e][dr];
      *(uint4*)(dst + (long)dr * SEQ + sc) = *(const uint4*)tmp;
    }
  }
}

// ---------------- flash attention v3 (r3 known-good): pipelined 2-barrier loop -------
// syncA -> issue V[kt] -> QK (covers V) -> exp/P -> syncB -> issue K[kt+1] -> PV.
// Fixed-max softmax (|score|<=16 since ||q||=||k||=16 after RMSnorm; RoPE norm-preserving).
// Split-K: chunk of 16 k-tiles; partials additive; combine does (O0+O1)/(l0+l1).
__global__ void __launch_bounds__(256) flash_attn(const u16* __restrict__ qkv,
                                                  const u16* __restrict__ vt,
                                                  u16* __restrict__ opart,
                                                  float* __restrict__ lpart) {
  const int bh = blockIdx.x, b = bh >> 3, h = bh & 7;
  const int qt = 31 - (int)blockIdx.y;          // heavy tiles dispatch first
  const int kc = blockIdx.z;
  if (kc && qt < 16) return;                    // no second chunk needed
  const int kt0 = kc * 16;
  const int kt_end = (qt < kt0 + 15) ? qt : (kt0 + 15);

  __shared__ __align__(16) u16 Ks[64 * 256];    // 32 KB (also Q staging at start)
  __shared__ __align__(16) u16 Vs[256 * 64];    // 32 KB
  __shared__ __align__(16) u16 Pb[4 * 16 * 64]; //  8 KB
  const int tid = threadIdx.x;
  const int wave = tid >> 6, lane = tid & 63;
  const int quad = lane >> 4, l16 = lane & 15;
  const long qbase = (long)(b * SEQ + qt * 64) * NQKV + h * HDIM;
  const long kbase = (long)(b * SEQ) * NQKV + EDIM + h * HDIM;
  const long vbase = (long)bh * HDIM * SEQ;

  // stage Q tile 64x256 into Ks
#pragma unroll
  for (int p = 0; p < 8; ++p) {
    const int o = p * 4096 + tid * 16;
    const int row = o >> 9;                        // 512B rows
    const int cg = ((o >> 4) & 31) ^ (row & 7);
    gload16(qkv + qbase + (long)row * NQKV + cg * 8, (char*)Ks + o);
  }
  __syncthreads();
  bf16x8 qf[8];
  {
    const int qr = wave * 16 + l16;
#pragma unroll
    for (int ks = 0; ks < 8; ++ks) {
      const int u = ks * 4 + quad;
      qf[ks] = *(const bf16x8*)(Ks + qr * 256 + (u ^ (qr & 7)) * 8);
    }
  }
  __syncthreads();   // all waves done reading Q before K[kt0] overwrites Ks

  // preload K[kt0]
#pragma unroll
  for (int p = 0; p < 8; ++p) {
    const int o = p * 4096 + tid * 16;
    const int row = o >> 9;
    const int cg = ((o >> 4) & 31) ^ (row & 7);
    gload16(qkv + kbase + (long)(kt0 * 64 + row) * NQKV + cg * 8, (char*)Ks + o);
  }

  const f32x4 fz = {0.f, 0.f, 0.f, 0.f};
  f32x4 O[16];
#pragma unroll
  for (int t = 0; t < 16; ++t) O[t] = fz;
  float lacc[4] = {0.f, 0.f, 0.f, 0.f};
  const float C1 = SCALE * LOG2E;       // exp2(S*C1 - C2) = exp(score - 16)
  const float C2 = 16.0f * LOG2E;

  for (int kt = kt0; kt <= kt_end; ++kt) {
    __syncthreads();  // syncA: K[kt] staged; prev PV done -> Vs free
    // issue V[kt] -> Vs; flight covered by QK below
#pragma unroll
    for (int p = 0; p < 8; ++p) {
      const int o = p * 4096 + tid * 16;
      const int row = o >> 7;                      // 128B rows
      const int cg = ((o >> 4) & 7) ^ (row & 7);
      gload16(vt + vbase + (long)row * SEQ + kt * 64 + cg * 8, (char*)Vs + o);
    }
    // S = Q·K^T : per wave 16 q-rows x 64 k-cols
    f32x4 S[4];
#pragma unroll
    for (int nt = 0; nt < 4; ++nt) S[nt] = fz;
#pragma unroll
    for (int nt = 0; nt < 4; ++nt) {
      const int kr = nt * 16 + l16;
#pragma unroll
      for (int ks = 0; ks < 8; ++ks) {
        const int u = ks * 4 + quad;
        const bf16x8 kf = *(const bf16x8*)(Ks + kr * 256 + (u ^ (kr & 7)) * 8);
        S[nt] = __builtin_amdgcn_mfma_f32_16x16x32_bf16(qf[ks], kf, S[nt], 0, 0, 0);
      }
    }
    // exp + write P to LDS (A-operand layout with swizzle)
    u16* Pw = Pb + wave * (16 * 64);
    if (kt == qt) {   // diagonal tile: causal mask (wave-uniform branch)
      const int qg0 = qt * 64 + wave * 16 + quad * 4;
      const int kg0 = kt * 64 + l16;
#pragma unroll
      for (int nt = 0; nt < 4; ++nt) {
        const int kg = kg0 + nt * 16;
#pragma unroll
        for (int r = 0; r < 4; ++r) {
          float p = exp2f(S[nt][r] * C1 - C2);
          p = (kg <= qg0 + r) ? p : 0.f;
          lacc[r] += p;
          const int qrow = quad * 4 + r;
          const int col = nt * 16 + l16;
          Pw[qrow * 64 + (((col >> 3) ^ (qrow & 7)) * 8) + (col & 7)] = f2bf(p);
        }
      }
    } else {
#pragma unroll
      for (int nt = 0; nt < 4; ++nt) {
#pragma unroll
        for (int r = 0; r < 4; ++r) {
          const float p = exp2f(S[nt][r] * C1 - C2);
          lacc[r] += p;
          const int qrow = quad * 4 + r;
          const int col = nt * 16 + l16;
          Pw[qrow * 64 + (((col >> 3) ^ (qrow & 7)) * 8) + (col & 7)] = f2bf(p);
        }
      }
    }
    __syncthreads();  // syncB: V[kt] staged; Ks reads done; P visible
    // issue K[kt+1] -> Ks; flight covered by PV below
    if (kt < kt_end) {
#pragma unroll
      for (int p = 0; p < 8; ++p) {
        const int o = p * 4096 + tid * 16;
        const int row = o >> 9;
        const int cg = ((o >> 4) & 31) ^ (row & 7);
        gload16(qkv + kbase + (long)((kt + 1) * 64 + row) * NQKV + cg * 8, (char*)Ks + o);
      }
    }
    // O += P·V
    bf16x8 pf[2];
#pragma unroll
    for (int ks = 0; ks < 2; ++ks) {
      const int u = ks * 4 + quad;
      pf[ks] = *(const bf16x8*)(Pw + l16 * 64 + (u ^ (l16 & 7)) * 8);
    }
#pragma unroll
    for (int nt = 0; nt < 16; ++nt) {
      const int vr = nt * 16 + l16;
#pragma unroll
      for (int ks = 0; ks < 2; ++ks) {
        const int u = ks * 4 + quad;
        const bf16x8 vf = *(const bf16x8*)(Vs + vr * 64 + (u ^ (vr & 7)) * 8);
        O[nt] = __builtin_amdgcn_mfma_f32_16x16x32_bf16(pf[ks], vf, O[nt], 0, 0, 0);
      }
    }
  }
  // reduce per-lane l partial across the 16 lanes sharing a row group
#pragma unroll
  for (int off = 1; off < 16; off <<= 1)
#pragma unroll
    for (int r = 0; r < 4; ++r) lacc[r] += __shfl_xor(lacc[r], off);

  const long pbase = ((long)(bh * 32 + qt) * 2 + kc) * (64 * 256);
#pragma unroll
  for (int nt = 0; nt < 16; ++nt) {
    const int col = nt * 16 + l16;
#pragma unroll
    for (int r = 0; r < 4; ++r) {
      const int qrow = wave * 16 + quad * 4 + r;
      opart[pbase + (long)qrow * 256 + col] = f2bf(O[nt][r]);
    }
  }
  if (l16 == 0) {
    const long lbase = ((long)(bh * 32 + qt) * 2 + kc) * 64;
#pragma unroll
    for (int r = 0; r < 4; ++r)
      lpart[lbase + wave * 16 + quad * 4 + r] = lacc[r];
  }
}

// ---------------- combine split-K partials: Ob = (O0 + O1) / (l0 + l1) ----------------
__global__ void __launch_bounds__(256) fa_combine(const u16* __restrict__ opart,
                                                  const float* __restrict__ lpart,
                                                  u16* __restrict__ ob) {
  const int bh = blockIdx.x, qt = blockIdx.y;
  const int b = bh >> 3, h = bh & 7;
  const bool two = (qt >= 16);
  const long p0 = ((long)(bh * 32 + qt) * 2) * (64 * 256);
  const long l0 = ((long)(bh * 32 + qt) * 2) * 64;
  __shared__ float rl[64];
  if (threadIdx.x < 64) {
    float l = lpart[l0 + threadIdx.x];
    if (two) l += lpart[l0 + 64 + threadIdx.x];
    rl[threadIdx.x] = 1.0f / l;
  }
  __syncthreads();
#pragma unroll
  for (int i = 0; i < 8; ++i) {
    const int e = i * 2048 + threadIdx.x * 8;
    const int row = e >> 8, d = e & 255;
    const u16* a = opart + p0 + e;
    float v[8];
#pragma unroll
    for (int j = 0; j < 8; ++j) v[j] = bf2f(a[j]);
    if (two) {
      const u16* c = a + 64 * 256;
#pragma unroll
      for (int j = 0; j < 8; ++j) v[j] += bf2f(c[j]);
    }
    const float inv = rl[row];
    u16 o[8];
#pragma unroll
    for (int j = 0; j < 8; ++j) o[j] = f2bf(v[j] * inv);
    *(uint4*)(ob + ((long)(b * SEQ + qt * 64 + row)) * EDIM + h * HDIM + d) =
        *(const uint4*)o;
  }
}

// ---------------- launch ----------------
extern "C" void kernel_launch(void* const* d_in, const int* in_sizes, int n_in,
                              void* d_out, int out_size, void* d_ws, size_t ws_size,
                              hipStream_t stream) {
  const float* x  = (const float*)d_in[0];
  const int* pos  = (const int*)d_in[1];
  const float* Wq = (const float*)d_in[2];
  const float* Wk = (const float*)d_in[3];
  const float* Wv = (const float*)d_in[4];
  const float* Wo = (const float*)d_in[5];
  const float* qw = (const float*)d_in[6];
  const float* kw = (const float*)d_in[7];

  char* ws = (char*)d_ws;
  u16* xb   = (u16*)(ws);                    // 16 MiB  x bf16 (4096x2048)   [dead after GEMM1]
  u16* Wcat = (u16*)(ws + 16777216L);        // 24 MiB  [Wq;Wk;Wv] bf16     [dead after GEMM1]
  u16* Wob  = (u16*)(ws + 41943040L);        //  8 MiB  Wo bf16
  u16* QKVb = (u16*)(ws + 50331648L);        // 48 MiB  qkv bf16 (4096x6144)
  u16* Vt   = (u16*)(ws + 100663296L);       // 16 MiB  V^T bf16 (16x256x2048)
  u16* Ob   = (u16*)(ws + 117440512L);       // 16 MiB  attn out bf16 (4096x2048)
  // flash partials overlay the dead xb/Wcat region (needs 32.25 MiB < 40 MiB):
  u16*   Opart = (u16*)(ws);                 // 32 MiB  (16*32*2) x 64 x 256 bf16
  float* Lpart = (float*)(ws + 33554432L);   // 256 KiB

  cast_all<<<24576, 256, 0, stream>>>((const float4*)x, (const float4*)Wq,
                                      (const float4*)Wk, (const float4*)Wv,
                                      (const float4*)Wo, (ushort4*)xb,
                                      (ushort4*)Wcat, (ushort4*)Wob);

  gemm_bt<1><<<dim3(32, 48), 256, 0, stream>>>(xb, Wcat, (void*)QKVb, NQKV, DIMM);
  norm_rope_tv<<<18432, 256, 0, stream>>>(QKVb, pos, qw, kw, Vt);
  flash_attn<<<dim3(16, 32, 2), 256, 0, stream>>>(QKVb, Vt, Opart, Lpart);
  fa_combine<<<dim3(16, 32), 256, 0, stream>>>(Opart, Lpart, Ob);
  gemm_bt<0><<<dim3(32, 16), 256, 0, stream>>>(Ob, Wob, d_out, EDIM, DIMM);
}